// Round 9
// baseline (66.230 us; speedup 1.0000x reference)
//
#include <hip/hip_runtime.h>

typedef float v2f __attribute__((ext_vector_type(2)));

constexpr int IN_D = 18, W_HID = 10, N_HID = 19;
constexpr float SLOPE = 0.1f;

__device__ __forceinline__ v2f splat(float s) { v2f v; v[0] = s; v[1] = s; return v; }

__device__ __forceinline__ v2f lrelu2(v2f x) {
    return __builtin_elementwise_max(x, x * splat(SLOPE));   // pk_mul + pk_max
}

// One 10->10 layer for FOUR independent 2-sample chains.
// Each weight scalar is used by 4 back-to-back pk-FMAs (amortizes any
// SGPR->VGPR materialization 4x and gives 4-way ILP).
__device__ __forceinline__ void layer10_x4(
    const v2f* __restrict__ iA, v2f* __restrict__ oA,
    const v2f* __restrict__ iB, v2f* __restrict__ oB,
    const v2f* __restrict__ iC, v2f* __restrict__ oC,
    const v2f* __restrict__ iD, v2f* __restrict__ oD,
    const float* __restrict__ W, const float* __restrict__ bb)
{
    #pragma unroll
    for (int j = 0; j < W_HID; ++j) {
        v2f aA = splat(bb[j]);
        v2f aB = aA, aC = aA, aD = aA;
        #pragma unroll
        for (int k = 0; k < W_HID; ++k) {
            const float w = W[j*W_HID + k];
            v2f wv = splat(w);
            aA = __builtin_elementwise_fma(iA[k], wv, aA);
            aB = __builtin_elementwise_fma(iB[k], wv, aB);
            aC = __builtin_elementwise_fma(iC[k], wv, aC);
            aD = __builtin_elementwise_fma(iD[k], wv, aD);
        }
        oA[j] = lrelu2(aA);
        oB[j] = lrelu2(aB);
        oC[j] = lrelu2(aC);
        oD[j] = lrelu2(aD);
    }
}

// Load 2 samples' inputs and run layer 0 (18->10) into h.
__device__ __forceinline__ void load_and_layer0(
    const float* __restrict__ state, const float* __restrict__ action,
    const float* __restrict__ W0, const float* __restrict__ bias0,
    int pairIdx, v2f* __restrict__ h)
{
    float Sf[24];
    {
        const float4* s4 = reinterpret_cast<const float4*>(state) + (size_t)pairIdx * 6;
        #pragma unroll
        for (int r = 0; r < 6; ++r) {
            float4 v = s4[r];
            Sf[4*r] = v.x; Sf[4*r+1] = v.y; Sf[4*r+2] = v.z; Sf[4*r+3] = v.w;
        }
    }
    float Af[12];
    {
        const float4* a4 = reinterpret_cast<const float4*>(action) + (size_t)pairIdx * 3;
        #pragma unroll
        for (int r = 0; r < 3; ++r) {
            float4 v = a4[r];
            Af[4*r] = v.x; Af[4*r+1] = v.y; Af[4*r+2] = v.z; Af[4*r+3] = v.w;
        }
    }
    v2f x[IN_D];
    #pragma unroll
    for (int k = 0; k < 12; ++k) { v2f v; v[0] = Sf[k]; v[1] = Sf[12 + k]; x[k] = v; }
    #pragma unroll
    for (int k = 0; k < 6; ++k)  { v2f v; v[0] = Af[k]; v[1] = Af[6 + k];  x[12 + k] = v; }

    #pragma unroll
    for (int j = 0; j < W_HID; ++j) {
        v2f acc = splat(bias0[j]);
        #pragma unroll
        for (int k = 0; k < IN_D; ++k)
            acc = __builtin_elementwise_fma(x[k], splat(W0[j*IN_D + k]), acc);
        h[j] = lrelu2(acc);
    }
}

// 8 samples/thread = 4 independent v2f chains; rolled hidden loop; SGPR weights
// each materialized once per 4 chains. 2 waves/SIMD (stall% shown wave-insensitive).
__global__ __launch_bounds__(256, 2) void critic_pk8(
    const float* __restrict__ state, const float* __restrict__ action,
    const float* __restrict__ W0, const float* __restrict__ bias0,
    const float* __restrict__ Ws, const float* __restrict__ bs,
    const float* __restrict__ Wf, const float* __restrict__ bf,
    float* __restrict__ out, int B)
{
    const int t = blockIdx.x * blockDim.x + threadIdx.x;
    if (t * 8 >= B) return;
    const int pair0 = t * 4;               // four 2-sample pairs: pair0 .. pair0+3

    v2f hA[W_HID], hB[W_HID], hC[W_HID], hD[W_HID];
    v2f gA[W_HID], gB[W_HID], gC[W_HID], gD[W_HID];

    load_and_layer0(state, action, W0, bias0, pair0 + 0, hA);
    load_and_layer0(state, action, W0, bias0, pair0 + 1, hB);
    load_and_layer0(state, action, W0, bias0, pair0 + 2, hC);
    load_and_layer0(state, action, W0, bias0, pair0 + 3, hD);

    // ---- hidden layers: rolled, 2 per iteration (ping-pong h->g->h) ----
    const float* __restrict__ W  = Ws;
    const float* __restrict__ bb = bs;
    #pragma unroll 1
    for (int it = 0; it < (N_HID - 1) / 2; ++it) {
        layer10_x4(hA, gA, hB, gB, hC, gC, hD, gD, W,               bb);
        layer10_x4(gA, hA, gB, hB, gC, hC, gD, hD, W + W_HID*W_HID, bb + W_HID);
        W  += 2 * W_HID * W_HID;
        bb += 2 * W_HID;
    }
    layer10_x4(hA, gA, hB, gB, hC, gC, hD, gD, W, bb);   // hidden layer 18

    // ---- final layer: 10 -> 1 for all 4 chains ----
    v2f aA = splat(bf[0]);
    v2f aB = aA, aC = aA, aD = aA;
    #pragma unroll
    for (int k = 0; k < W_HID; ++k) {
        v2f wv = splat(Wf[k]);
        aA = __builtin_elementwise_fma(gA[k], wv, aA);
        aB = __builtin_elementwise_fma(gB[k], wv, aB);
        aC = __builtin_elementwise_fma(gC[k], wv, aC);
        aD = __builtin_elementwise_fma(gD[k], wv, aD);
    }
    aA = lrelu2(aA); aB = lrelu2(aB); aC = lrelu2(aC); aD = lrelu2(aD);

    float4 o0; o0.x = aA[0]; o0.y = aA[1]; o0.z = aB[0]; o0.w = aB[1];
    float4 o1; o1.x = aC[0]; o1.y = aC[1]; o1.z = aD[0]; o1.w = aD[1];
    float4* op = reinterpret_cast<float4*>(out) + (size_t)t * 2;
    op[0] = o0;
    op[1] = o1;
}

extern "C" void kernel_launch(void* const* d_in, const int* in_sizes, int n_in,
                              void* d_out, int out_size, void* d_ws, size_t ws_size,
                              hipStream_t stream) {
    const float* state  = (const float*)d_in[0];
    const float* action = (const float*)d_in[1];
    const float* W0     = (const float*)d_in[2];
    const float* b0     = (const float*)d_in[3];
    const float* Ws     = (const float*)d_in[4];
    const float* bs     = (const float*)d_in[5];
    const float* Wf     = (const float*)d_in[6];
    const float* bf     = (const float*)d_in[7];
    float* out = (float*)d_out;

    const int B = out_size;                  // [1, B] flat; B = 1048576 (div by 8)
    const int nthreads = B / 8;              // 8 samples per thread
    const int block = 256;
    const int grid = (nthreads + block - 1) / block;
    critic_pk8<<<grid, block, 0, stream>>>(state, action, W0, b0, Ws, bs, Wf, bf, out, B);
}